// Round 1
// baseline (279.649 us; speedup 1.0000x reference)
//
#include <hip/hip_runtime.h>
#include <hip/hip_bf16.h>
#include <stdint.h>

#define E_EDGES 100000
#define IN_F    256
#define HID     128
#define KNB     16
#define NCHUNK  ((E_EDGES + 63) / 64)   // 1563
#define GEMM_GRID 512

// ---- sliced gather parameters ----
#define NS          16                   // T-row slices (6250 rows = 1.6 MB each, fits per-XCD L2)
#define SLICE_ROWS  6250
#define GCHUNKS     8                    // edge-chunks of 16 per block -> 128 edges/block
#define EDGES_PER_BLK (GCHUNKS * 16)     // 128
#define GATHER_GRID ((E_EDGES + EDGES_PER_BLK - 1) / EDGES_PER_BLK)   // 782 (co-resident at 4 blk/CU)

typedef short bf16x8 __attribute__((ext_vector_type(8)));
typedef float f32x4  __attribute__((ext_vector_type(4)));

__device__ __forceinline__ unsigned short f2bf(float f) {
    union { float f; unsigned u; } v; v.f = f;
    unsigned u = v.u;
    u += 0x7fffu + ((u >> 16) & 1u);   // round-to-nearest-even
    return (unsigned short)(u >> 16);
}

// W [256][128] fp32 -> Wtf: bf16 in MFMA B-fragment order.
__global__ void conv_w_kernel(const float* __restrict__ W, unsigned short* __restrict__ Wtf) {
    int d = blockIdx.x * 256 + threadIdx.x;   // 0..4095
    int f = d >> 6, L = d & 63;
    int k0 = f >> 3, ct = f & 7, quad = L >> 4, l15 = L & 15;
    int n  = ct * 16 + l15;
    int kb = (k0 * 4 + quad) * 8;
    const float* wp = W + (size_t)kb * HID + n;
    unsigned short h[8];
    #pragma unroll
    for (int j = 0; j < 8; ++j) h[j] = f2bf(wp[(size_t)j * HID]);
    uint4 o;
    o.x = (unsigned)h[0] | ((unsigned)h[1] << 16);
    o.y = (unsigned)h[2] | ((unsigned)h[3] << 16);
    o.z = (unsigned)h[4] | ((unsigned)h[5] << 16);
    o.w = (unsigned)h[6] | ((unsigned)h[7] << 16);
    *(uint4*)(Wtf + (size_t)d * 8) = o;
}

// T = A @ W + b (A fp32, converted in-reg), stored bf16 [E][128]. (unchanged)
__launch_bounds__(256, 2)
__global__ void gemm_t_kernel(const float* __restrict__ A,
                              const unsigned short* __restrict__ Wtf,
                              const float* __restrict__ bias,
                              unsigned short* __restrict__ T) {
    __shared__ unsigned short Bs[32768];   // 64 KB, fragment order
    const int tid  = threadIdx.x;
    const int wave = tid >> 6;
    const int lane = tid & 63;
    const int l15  = lane & 15;
    const int quad = lane >> 4;

    int c = blockIdx.x;
    int arow = c * 64 + wave * 16 + l15;
    if (arow >= E_EDGES) arow = E_EDGES - 1;
    const float* ap = A + (size_t)arow * IN_F + quad * 8;
    float4 af32[16];
    #pragma unroll
    for (int k0 = 0; k0 < 8; ++k0) {
        af32[2 * k0]     = *(const float4*)(ap + k0 * 32);
        af32[2 * k0 + 1] = *(const float4*)(ap + k0 * 32 + 4);
    }

    #pragma unroll
    for (int it = 0; it < 16; ++it) {
        int d = it * 256 + tid;
        *(uint4*)(Bs + (size_t)d * 8) = *(const uint4*)(Wtf + (size_t)d * 8);
    }

    float4 bv4[8];
    #pragma unroll
    for (int ct = 0; ct < 8; ++ct)
        bv4[ct] = *(const float4*)(bias + ct * 16 + quad * 4);

    __syncthreads();

    for (; c < NCHUNK; c += GEMM_GRID) {
        bf16x8 apre[8];
        #pragma unroll
        for (int k0 = 0; k0 < 8; ++k0) {
            float4 lo = af32[2 * k0], hi = af32[2 * k0 + 1];
            bf16x8 f;
            f[0] = (short)f2bf(lo.x); f[1] = (short)f2bf(lo.y);
            f[2] = (short)f2bf(lo.z); f[3] = (short)f2bf(lo.w);
            f[4] = (short)f2bf(hi.x); f[5] = (short)f2bf(hi.y);
            f[6] = (short)f2bf(hi.z); f[7] = (short)f2bf(hi.w);
            apre[k0] = f;
        }

        {
            int cn = c + GEMM_GRID;
            int arow2 = cn * 64 + wave * 16 + l15;
            if (arow2 >= E_EDGES) arow2 = E_EDGES - 1;
            const float* ap2 = A + (size_t)arow2 * IN_F + quad * 8;
            #pragma unroll
            for (int k0 = 0; k0 < 8; ++k0) {
                af32[2 * k0]     = *(const float4*)(ap2 + k0 * 32);
                af32[2 * k0 + 1] = *(const float4*)(ap2 + k0 * 32 + 4);
            }
        }
        __builtin_amdgcn_sched_barrier(0);

        f32x4 acc[8] = {};
        #pragma unroll
        for (int k0 = 0; k0 < 8; ++k0) {
            #pragma unroll
            for (int ct = 0; ct < 8; ++ct) {
                bf16x8 bf = *(const bf16x8*)(Bs + ((size_t)((k0 * 8 + ct) * 64 + lane)) * 8);
                acc[ct] = __builtin_amdgcn_mfma_f32_16x16x32_bf16(bf, apre[k0], acc[ct], 0, 0, 0);
            }
        }

        const int row = c * 64 + wave * 16 + l15;
        if (row < E_EDGES) {
            unsigned short* tp = T + (size_t)row * HID + quad * 4;
            #pragma unroll
            for (int ct = 0; ct < 8; ++ct) {
                unsigned short h0 = f2bf(acc[ct][0] + bv4[ct].x);
                unsigned short h1 = f2bf(acc[ct][1] + bv4[ct].y);
                unsigned short h2 = f2bf(acc[ct][2] + bv4[ct].z);
                unsigned short h3 = f2bf(acc[ct][3] + bv4[ct].w);
                uint2 o;
                o.x = (unsigned)h0 | ((unsigned)h1 << 16);
                o.y = (unsigned)h2 | ((unsigned)h3 << 16);
                *(uint2*)(tp + ct * 16) = o;
            }
        }
    }
}

__device__ __forceinline__ void acc_bf16x8(float a[8], uint4 v) {
    unsigned w[4] = { v.x, v.y, v.z, v.w };
    union { unsigned u; float f; } c;
    #pragma unroll
    for (int j = 0; j < 4; ++j) {
        c.u = w[j] << 16;          a[2 * j]     += c.f;
        c.u = w[j] & 0xffff0000u;  a[2 * j + 1] += c.f;
    }
}

// out[i] = t[i] + sum_k t[nbr[i][k]]  (fp32 accumulate from bf16 t)
//
// SLICED gather for L2 residency: each edge's 17 row indices (16 nbrs + self)
// are counting-sorted into NS=16 slices of 6250 T-rows (1.6 MB bf16 each,
// << 4 MiB per-XCD L2). A persistent, fully co-resident grid (782 blocks x
// 256 thr, <=4 blk/CU) sweeps slices in order; within a slice every block's
// random reads hit the same 1.6 MB window -> L2 hits instead of L2 misses.
// Accumulators for the block's 128 edges live in registers across the whole
// sweep (acc[8][8]/thread); out is written once at the end, so the store
// stream never pollutes L2 during the sweep.
// Thread map: el = tid>>4 (edge-in-chunk), lane = tid&15 (feats lane*8..+8).
__launch_bounds__(256, 4)
__global__ void gather_sum_kernel(const unsigned short* __restrict__ T,
                                  const int* __restrict__ nbr,
                                  float* __restrict__ out) {
    __shared__ int sidx[EDGES_PER_BLK * 16];        // staged neighbor lists (8 KB)
    __shared__ int ssort[EDGES_PER_BLK * 17];       // slice-sorted indices (8.7 KB)
    __shared__ int soff[EDGES_PER_BLK * 17];        // per-edge slice offsets, 17 ea (8.7 KB)
    __shared__ int scur[EDGES_PER_BLK * 17];        // scratch cursors, stride 17 vs banks (8.7 KB)

    const int tid   = threadIdx.x;
    const int edge0 = blockIdx.x * EDGES_PER_BLK;
    const int el    = tid >> 4;
    const int lane  = tid & 15;

    // Stage neighbor lists: 2048 ints, 8 per thread, coalesced uint4 pairs.
    {
        int g = edge0 * KNB + tid * 8;
        if (g > E_EDGES * KNB - 8) g = E_EDGES * KNB - 8;   // clamp (last block only)
        const uint4* np = (const uint4*)(nbr + g);
        *(uint4*)(sidx + tid * 8)     = np[0];
        *(uint4*)(sidx + tid * 8 + 4) = np[1];
    }
    __syncthreads();

    // Counting sort of 17 indices per edge into NS slices (1 thread / edge).
    if (tid < EDGES_PER_BLK) {
        const int t = tid;
        unsigned self = (unsigned)(edge0 + t);
        if (self > E_EDGES - 1) self = E_EDGES - 1;

        #pragma unroll
        for (int s = 0; s < NS; ++s) scur[t * 17 + s] = 0;
        #pragma unroll
        for (int k = 0; k < KNB; ++k) {
            unsigned idx = (unsigned)sidx[t * 16 + k];
            scur[t * 17 + idx / SLICE_ROWS] += 1;
        }
        scur[t * 17 + self / SLICE_ROWS] += 1;

        int run = 0;
        soff[t * 17 + 0] = 0;
        #pragma unroll
        for (int s = 0; s < NS; ++s) {
            run += scur[t * 17 + s];
            soff[t * 17 + s + 1] = run;
        }
        #pragma unroll
        for (int s = 0; s < NS; ++s) scur[t * 17 + s] = soff[t * 17 + s];

        #pragma unroll
        for (int k = 0; k < KNB; ++k) {
            unsigned idx = (unsigned)sidx[t * 16 + k];
            int s = idx / SLICE_ROWS;
            ssort[t * 17 + scur[t * 17 + s]++] = (int)idx;
        }
        {
            int s = self / SLICE_ROWS;
            ssort[t * 17 + scur[t * 17 + s]++] = (int)self;
        }
    }
    __syncthreads();

    const unsigned short* Tb = T + (size_t)lane * 8;

    float acc[GCHUNKS][8] = {};
    int   cur[GCHUNKS];
    #pragma unroll
    for (int c = 0; c < GCHUNKS; ++c) cur[c] = 0;   // soff[e*17+0] == 0

    for (int s = 0; s < NS; ++s) {
        #pragma unroll
        for (int c = 0; c < GCHUNKS; ++c) {
            const int e   = c * 16 + el;
            int j         = cur[c];
            const int end = soff[e * 17 + s + 1];
            cur[c] = end;
            if (j < end) {
                // 2-deep pipeline: issue next row load before consuming current.
                int idx = ssort[e * 17 + j];
                uint4 v = *(const uint4*)(Tb + (size_t)idx * HID);
                for (++j; j < end; ++j) {
                    int idx2 = ssort[e * 17 + j];
                    uint4 v2 = *(const uint4*)(Tb + (size_t)idx2 * HID);
                    acc_bf16x8(acc[c], v);
                    v = v2;
                }
                acc_bf16x8(acc[c], v);
            }
        }
    }

    #pragma unroll
    for (int c = 0; c < GCHUNKS; ++c) {
        const int edge = edge0 + c * 16 + el;
        if (edge < E_EDGES) {
            float* op = out + (size_t)edge * HID + lane * 8;
            float4 o0 = { acc[c][0], acc[c][1], acc[c][2], acc[c][3] };
            float4 o1 = { acc[c][4], acc[c][5], acc[c][6], acc[c][7] };
            *(float4*)op       = o0;
            *(float4*)(op + 4) = o1;
        }
    }
}

extern "C" void kernel_launch(void* const* d_in, const int* in_sizes, int n_in,
                              void* d_out, int out_size, void* d_ws, size_t ws_size,
                              hipStream_t stream) {
    const float* edge_feats = (const float*)d_in[0];   // [E, 256] fp32
    const int*   neighbors  = (const int*)d_in[1];     // [E, 16] int32
    const float* W          = (const float*)d_in[2];   // [256, 128] fp32
    const float* b          = (const float*)d_in[3];   // [128] fp32
    float*       out        = (float*)d_out;           // [E, 128] fp32

    unsigned short* Wtf = (unsigned short*)d_ws;                      // 64 KB, fragment order
    unsigned short* T   = (unsigned short*)d_ws + (size_t)IN_F * HID; // 25.6 MB

    conv_w_kernel<<<16, 256, 0, stream>>>(W, Wtf);
    gemm_t_kernel<<<GEMM_GRID, 256, 0, stream>>>(edge_feats, Wtf, b, T);
    gather_sum_kernel<<<GATHER_GRID, 256, 0, stream>>>(T, neighbors, out);
}